// Round 8
// baseline (61.193 us; speedup 1.0000x reference)
//
#include <hip/hip_runtime.h>
#include <hip/hip_bf16.h>
#include <math.h>

#define B_ 16
#define T_ 128
#define H_ 8
#define N_ 64
#define NCHUNK 8
#define CHUNK (T_ / NCHUNK)   // 16
#define NXCD 8

#define K_ENT 4.0f   // variance shift for entropy (ent ~ 3.9); exact math for any K
#define K_DIF 0.75f  // variance shift for diff

typedef float f32x4 __attribute__((ext_vector_type(4)));

__device__ __forceinline__ f32x4 ntload(const float* p) {
  return __builtin_nontemporal_load((const f32x4*)p);
}

// ---- cross-lane add helpers -------------------------------------------------
template <int CTRL>
__device__ __forceinline__ float dpp_xadd(float x) {
  const int yi = __builtin_amdgcn_update_dpp(
      __float_as_int(x), __float_as_int(x), CTRL, 0xf, 0xf, false);
  return x + __int_as_float(yi);
}
template <int IMM>
__device__ __forceinline__ float swz_xadd(float x) {
  return x + __int_as_float(
                 __builtin_amdgcn_ds_swizzle(__float_as_int(x), IMM));
}
// sum over a 16-lane column group: masks {1,2,4,8}
// xor1=quad_perm[1,0,3,2](0xB1), xor2=quad_perm[2,3,0,1](0x4E),
// xor4=ds_swizzle(0x101F), xor8=row_ror:8(0x128, exact for sum within 16).
__device__ __forceinline__ float g16sum(float x) {
  x = dpp_xadd<0xB1>(x);
  x = dpp_xadd<0x4E>(x);
  x = swz_xadd<0x101F>(x);
  x = dpp_xadd<0x128>(x);
  return x;
}

// ---------------------------------------------------------------------------
// Kernel 1: one WAVE per (b, c, n-quad). Per timestep, 8 load instructions
// (one per head), each a DENSE CONTIGUOUS 1 KB: lane l covers row nq*4+(l>>4),
// cols 4*(l&15)..+3 of head-slab h. Softmax S,D reduce over the 16-lane
// column group; head-mean is pure in-register accumulation over the 8
// per-head register sets. diff/diag stay in-wave (prev = 32 VGPR).
// ---------------------------------------------------------------------------
__global__ __launch_bounds__(256, 2) void feat_partial_kernel(
    const float* __restrict__ sat, float* __restrict__ part) {
  const int wave = threadIdx.x >> 6;
  const int lane = threadIdx.x & 63;
  const int cpx = (B_ * NCHUNK * 16 / 4) / NXCD;   // 64 blocks per XCD
  const int bid = (blockIdx.x & (NXCD - 1)) * cpx + (blockIdx.x >> 3);
  const int unit = bid * 4 + wave;   // (b*NCHUNK + c)*16 + nq
  const int nq = unit & 15;          // per-wave (block-uniform b,c)
  const int bc = unit >> 4;
  const int c = bc & (NCHUNK - 1);
  const int b = bc >> 3;             // NCHUNK == 8

  const int g = lane >> 4;   // row within the quad
  const int p = lane & 15;   // column-group index

  const int t0 = c * CHUNK;
  const int tstart = (c == 0) ? 0 : t0 - 1;
  const int tend = t0 + CHUNK;

  // diag of row n=nq*4+g is col n = 4*nq+g -> lane with p==nq, element g.
  float msel4[4];
#pragma unroll
  for (int j = 0; j < 4; ++j)
    msel4[j] = (p == nq && j == g) ? 0.125f : 0.f;   // fold the head-mean /8

  float prev[8][4];
#pragma unroll
  for (int h = 0; h < 8; ++h)
#pragma unroll
    for (int j = 0; j < 4; ++j) prev[h][j] = 0.f;

  float ent_sum = 0.f, ent_s2 = 0.f, ent_max = -1e30f, ent_min = 1e30f;
  float ent_first = 0.f, ent_last = 0.f;
  float diff_sum = 0.f, diff_s2 = 0.f, diff_max = -1e30f;
  float diag_sum = 0.f, diag_s2 = 0.f;

  const size_t slab0 = ((size_t)(b * T_ + tstart) * H_) << 12;  // elems
  const size_t tslab = (size_t)H_ << 12;                        // 32768 elems
  const int loff = (nq << 8) + (lane << 2);

  f32x4 cur[8];
  {
    const float* sp = sat + slab0 + loff;
#pragma unroll
    for (int h = 0; h < 8; ++h) cur[h] = ntload(sp + (h << 12));
  }

  for (int t = tstart; t < tend; ++t) {
    f32x4 nxt[8];
    const bool more = (t + 1 < tend);
    if (more) {
      const float* sp = sat + slab0 + (size_t)(t + 1 - tstart) * tslab + loff;
#pragma unroll
      for (int h = 0; h < 8; ++h) nxt[h] = ntload(sp + (h << 12));
    }

    float ent_acc = 0.f, dl = 0.f, dg = 0.f;
#pragma unroll
    for (int h = 0; h < 8; ++h) {
      const float x0 = cur[h][0], x1 = cur[h][1], x2 = cur[h][2], x3 = cur[h][3];
      const float e0 = __expf(x0), e1 = __expf(x1), e2 = __expf(x2), e3 = __expf(x3);
      float s = (e0 + e1) + (e2 + e3);
      float d = e0 * x0 + e1 * x1 + e2 * x2 + e3 * x3;
      s = g16sum(s);   // row sum over 64 cols (16 lanes x 4)
      d = g16sum(d);
      const float inv = 1.0f / s;
      ent_acc += __logf(s) - d * inv;   // -sum p ln p (EPS clip inactive)
      const float p0 = e0 * inv, p1 = e1 * inv, p2 = e2 * inv, p3 = e3 * inv;
      dl += fabsf(p0 - prev[h][0]) + fabsf(p1 - prev[h][1]) +
            fabsf(p2 - prev[h][2]) + fabsf(p3 - prev[h][3]);
      dg += p0 * msel4[0] + p1 * msel4[1] + p2 * msel4[2] + p3 * msel4[3];
      prev[h][0] = p0; prev[h][1] = p1; prev[h][2] = p2; prev[h][3] = p3;
    }
    const float ent_t = ent_acc * 0.125f;   // identical across the 16-group
    const float dl_t = g16sum(dl) * 0.125f;
    const float dg_t = g16sum(dg);          // 0.125 folded into msel4

    if (t >= t0) {
      const float z = ent_t - K_ENT;
      ent_sum += ent_t;
      ent_s2 += z * z;
      ent_max = fmaxf(ent_max, ent_t);
      ent_min = fminf(ent_min, ent_t);
      if (t > tstart) {  // diff defined for t>=1; overlap row feeds prev only
        const float w = dl_t - K_DIF;
        diff_sum += dl_t;
        diff_s2 += w * w;
        diff_max = fmaxf(diff_max, dl_t);
      }
      diag_sum += dg_t;
      diag_s2 += dg_t * dg_t;
      if (t == 0) ent_first = ent_t;
      if (t == T_ - 1) ent_last = ent_t;
    }

    if (more) {
#pragma unroll
      for (int h = 0; h < 8; ++h) cur[h] = nxt[h];
    }
  }

  // write 11 stats for row n = nq*4+g; lane (g,p) writes stat index p
  if (p < 11) {
    float v = 0.f;
    switch (p) {
      case 0:  v = ent_sum;  break;
      case 1:  v = ent_s2;   break;
      case 2:  v = ent_max;  break;
      case 3:  v = ent_min;  break;
      case 4:  v = ent_first; break;
      case 5:  v = ent_last; break;
      case 6:  v = diff_sum; break;
      case 7:  v = diff_s2;  break;
      case 8:  v = diff_max; break;
      case 9:  v = diag_sum; break;
      case 10: v = diag_s2;  break;
    }
    part[(size_t)((b * N_ + nq * 4 + g) * NCHUNK + c) * 12 + p] = v;
  }
}

// ---------------------------------------------------------------------------
// Kernel 2: per-batch combine -> 9 features/node -> LayerNorm -> 576x64 matvec
// + ReLU. 256 threads: wave 0 does stats+LN into LDS; all 4 waves split the
// 576-long dot product 4-way then LDS-reduce.
// ---------------------------------------------------------------------------
__global__ __launch_bounds__(256) void head_kernel(
    const float* __restrict__ part, const float* __restrict__ gamma,
    const float* __restrict__ beta, const float* __restrict__ W,
    const float* __restrict__ bias, float* __restrict__ out) {
  const int b = blockIdx.x;
  const int tid = threadIdx.x;
  const int lane = tid & 63;   // output column / node index
  const int wv = tid >> 6;     // k-segment

  __shared__ float xn[N_ * 9];
  __shared__ float red[4][N_];

  if (wv == 0) {
    float ent_sum = 0.f, ent_s2 = 0.f, ent_max = -1e30f, ent_min = 1e30f;
    float ent_first = 0.f, ent_last = 0.f;
    float diff_sum = 0.f, diff_s2 = 0.f, diff_max = -1e30f;
    float diag_sum = 0.f, diag_s2 = 0.f;

    const float* base = part + ((size_t)b * N_ + lane) * NCHUNK * 12;
#pragma unroll
    for (int c = 0; c < NCHUNK; ++c) {
      const float* o = base + c * 12;
      ent_sum += o[0];
      ent_s2 += o[1];
      ent_max = fmaxf(ent_max, o[2]);
      ent_min = fminf(ent_min, o[3]);
      if (c == 0) ent_first = o[4];
      if (c == NCHUNK - 1) ent_last = o[5];
      diff_sum += o[6];
      diff_s2 += o[7];
      diff_max = fmaxf(diff_max, o[8]);
      diag_sum += o[9];
      diag_s2 += o[10];
    }

    float f[9];
    const float em = ent_sum * (1.f / 128.f);
    const float emz = em - K_ENT;
    f[0] = em;
    f[1] = sqrtf(fmaxf(ent_s2 * (1.f / 128.f) - emz * emz, 0.f));
    f[2] = ent_max - ent_min;
    f[3] = (ent_last - ent_first) * (1.f / 127.f);
    const float dm = diff_sum * (1.f / 127.f);
    const float dmz = dm - K_DIF;
    f[4] = dm;
    f[5] = sqrtf(fmaxf(diff_s2 * (1.f / 127.f) - dmz * dmz, 0.f));
    f[6] = diff_max;
    const float gm = diag_sum * (1.f / 128.f);
    f[7] = gm;
    f[8] = sqrtf(fmaxf(diag_s2 * (1.f / 128.f) - gm * gm, 0.f));

    // LayerNorm over the 576 features
    float ls = 0.f;
#pragma unroll
    for (int k = 0; k < 9; ++k) ls += f[k];
#pragma unroll
    for (int w = 1; w < 64; w <<= 1) ls += __shfl_xor(ls, w, 64);
    const float mu = ls * (1.f / 576.f);

    float lv = 0.f;
#pragma unroll
    for (int k = 0; k < 9; ++k) {
      const float dd = f[k] - mu;
      lv += dd * dd;
    }
#pragma unroll
    for (int w = 1; w < 64; w <<= 1) lv += __shfl_xor(lv, w, 64);
    const float rstd = rsqrtf(lv * (1.f / 576.f) + 1e-5f);

#pragma unroll
    for (int k = 0; k < 9; ++k) {
      const int idx = lane * 9 + k;
      xn[idx] = (f[k] - mu) * rstd * gamma[idx] + beta[idx];
    }
  }
  __syncthreads();

  // out[b, col] = relu(sum_k xn[k] * W[k,col] + bias[col]); k split 4-way
  float acc = 0.f;
  const int k0 = wv * 144;
#pragma unroll 8
  for (int k = k0; k < k0 + 144; ++k) acc = fmaf(xn[k], W[k * 64 + lane], acc);
  red[wv][lane] = acc;
  __syncthreads();

  if (wv == 0) {
    const float r =
        red[0][lane] + red[1][lane] + red[2][lane] + red[3][lane] + bias[lane];
    out[b * 64 + lane] = fmaxf(r, 0.f);
  }
}

extern "C" void kernel_launch(void* const* d_in, const int* in_sizes, int n_in,
                              void* d_out, int out_size, void* d_ws,
                              size_t ws_size, hipStream_t stream) {
  const float* sat = (const float*)d_in[0];
  const float* gamma = (const float*)d_in[1];
  const float* beta = (const float*)d_in[2];
  const float* W = (const float*)d_in[3];
  const float* bias = (const float*)d_in[4];
  float* out = (float*)d_out;
  float* part = (float*)d_ws;  // 16*64*8*12 floats = 384 KiB

  feat_partial_kernel<<<B_ * NCHUNK * 16 / 4, 256, 0, stream>>>(sat, part);
  head_kernel<<<B_, 256, 0, stream>>>(part, gamma, beta, W, bias, out);
}